// Round 1
// baseline (2790.502 us; speedup 1.0000x reference)
//
#include <hip/hip_runtime.h>

// Problem constants: B=8, C=512, L=4096, Ci=256, K=L/2=2048
#define BATCH 8
#define CIN   512
#define LEN   4096
#define CI    256
#define KLEN  2048

// ---------------------------------------------------------------------------
// Kernel 1: theta/phi/g projections.  out[o,l] = sum_c W[o,c] x[c,l] + b[o]
// phi/g get maxpool2 along l fused in the epilogue.
// Grid: (L/64, 12, B). blockIdx.y: 0-3 theta rows, 4-7 phi, 8-11 g.
// ---------------------------------------------------------------------------
__global__ __launch_bounds__(256) void proj_kernel(
    const float* __restrict__ x,
    const float* __restrict__ tw, const float* __restrict__ tb,
    const float* __restrict__ pw, const float* __restrict__ pb,
    const float* __restrict__ gw, const float* __restrict__ gb,
    float* __restrict__ theta, float* __restrict__ phi, float* __restrict__ g)
{
    __shared__ float xs[32][68];   // [c][l] tile, pad 4 -> float4-aligned rows
    __shared__ float wt[32][68];   // [c][o] tile (W transposed)

    const int b  = blockIdx.z;
    const int ot = blockIdx.y;
    const int l0 = blockIdx.x * 64;
    const int which = ot >> 2;
    const int orow0 = (ot & 3) * 64;

    const float* W  = (which == 0) ? tw : ((which == 1) ? pw : gw);
    const float* Bs = (which == 0) ? tb : ((which == 1) ? pb : gb);

    const int t  = threadIdx.x;
    const int ty = t >> 4;     // 0..15 -> o block of 4
    const int tx = t & 15;     // 0..15 -> l block of 4

    float acc[4][4] = {};
    const float* xb = x + (size_t)b * CIN * LEN + l0;

    for (int c0 = 0; c0 < CIN; c0 += 32) {
        __syncthreads();
        // x tile [32 c][64 l]
        #pragma unroll
        for (int ii = 0; ii < 2; ii++) {
            int fid = t + 256 * ii;              // 512 float4s
            int row = fid >> 4, col = (fid & 15) << 2;
            *(float4*)&xs[row][col] =
                *(const float4*)(xb + (size_t)(c0 + row) * LEN + col);
        }
        // W tile [64 o][32 c] -> transposed into wt[c][o]
        #pragma unroll
        for (int ii = 0; ii < 2; ii++) {
            int fid = t + 256 * ii;              // 512 float4s
            int o = fid >> 3, c4 = (fid & 7) << 2;
            float4 v = *(const float4*)(W + (size_t)(orow0 + o) * CIN + c0 + c4);
            wt[c4 + 0][o] = v.x; wt[c4 + 1][o] = v.y;
            wt[c4 + 2][o] = v.z; wt[c4 + 3][o] = v.w;
        }
        __syncthreads();
        #pragma unroll
        for (int k = 0; k < 32; k++) {
            float4 a  = *(const float4*)&wt[k][ty << 2];
            float4 bb = *(const float4*)&xs[k][tx << 2];
            acc[0][0] += a.x * bb.x; acc[0][1] += a.x * bb.y;
            acc[0][2] += a.x * bb.z; acc[0][3] += a.x * bb.w;
            acc[1][0] += a.y * bb.x; acc[1][1] += a.y * bb.y;
            acc[1][2] += a.y * bb.z; acc[1][3] += a.y * bb.w;
            acc[2][0] += a.z * bb.x; acc[2][1] += a.z * bb.y;
            acc[2][2] += a.z * bb.z; acc[2][3] += a.z * bb.w;
            acc[3][0] += a.w * bb.x; acc[3][1] += a.w * bb.y;
            acc[3][2] += a.w * bb.z; acc[3][3] += a.w * bb.w;
        }
    }

    if (which == 0) {
        #pragma unroll
        for (int u = 0; u < 4; u++) {
            int o = orow0 + (ty << 2) + u;
            float bias = Bs[o];
            float4 v = make_float4(acc[u][0] + bias, acc[u][1] + bias,
                                   acc[u][2] + bias, acc[u][3] + bias);
            *(float4*)(theta + ((size_t)b * CI + o) * LEN + l0 + (tx << 2)) = v;
        }
    } else {
        float* outp = (which == 1) ? phi : g;
        #pragma unroll
        for (int u = 0; u < 4; u++) {
            int o = orow0 + (ty << 2) + u;
            float bias = Bs[o];
            float2 v;
            v.x = fmaxf(acc[u][0] + bias, acc[u][1] + bias);
            v.y = fmaxf(acc[u][2] + bias, acc[u][3] + bias);
            *(float2*)(outp + ((size_t)b * CI + o) * KLEN + (l0 >> 1) + (tx << 1)) = v;
        }
    }
}

// ---------------------------------------------------------------------------
// Kernel 2: flash attention.  S = theta^T phi (over c), online softmax over k,
// y[c,q] = sum_k P[q,k] g[c,k].  Qt=32, Kt=128, c-chunk 32.
// Grid: (L/32, B), 256 threads.
// ---------------------------------------------------------------------------
__global__ __launch_bounds__(256) void attn_kernel(
    const float* __restrict__ theta, const float* __restrict__ phi,
    const float* __restrict__ gbuf, float* __restrict__ y)
{
    __shared__ float th_s[256][36];    // theta block [c][q], pad to 36
    __shared__ float pg_s[32][132];    // phi/g chunk [c][k], pad to 132
    __shared__ float p_s[32][132];     // probabilities [q][k]
    __shared__ float row_m[32], row_l[32], row_a[32];

    const int b  = blockIdx.y;
    const int q0 = blockIdx.x * 32;
    const int t  = threadIdx.x;
    const int qy = t >> 4;   // q pair index 0..15
    const int kx = t & 15;   // S-phase k group
    const int cg = t & 15;   // y-phase c group

    const float* thb = theta + (size_t)b * CI * LEN + q0;
    #pragma unroll
    for (int ii = 0; ii < 8; ii++) {
        int fid = t + 256 * ii;           // 2048 float4s (256 rows x 8)
        int row = fid >> 3, col = (fid & 7) << 2;
        *(float4*)&th_s[row][col] = *(const float4*)(thb + (size_t)row * LEN + col);
    }
    if (t < 32) { row_m[t] = -3.0e38f; row_l[t] = 0.0f; }
    float O0[16], O1[16];
    #pragma unroll
    for (int j = 0; j < 16; j++) { O0[j] = 0.0f; O1[j] = 0.0f; }
    __syncthreads();

    for (int kt = 0; kt < 16; kt++) {
        float S0[8], S1[8];
        #pragma unroll
        for (int j = 0; j < 8; j++) { S0[j] = 0.0f; S1[j] = 0.0f; }

        const float* phb = phi + (size_t)b * CI * KLEN + kt * 128;
        for (int ch = 0; ch < 8; ch++) {
            __syncthreads();
            #pragma unroll
            for (int ii = 0; ii < 4; ii++) {
                int fid = t + 256 * ii;       // 1024 float4s (32 rows x 32)
                int row = fid >> 5, col = (fid & 31) << 2;
                *(float4*)&pg_s[row][col] =
                    *(const float4*)(phb + (size_t)(ch * 32 + row) * KLEN + col);
            }
            __syncthreads();
            #pragma unroll
            for (int cc = 0; cc < 32; cc++) {
                float2 a  = *(const float2*)&th_s[ch * 32 + cc][qy << 1];
                float4 v0 = *(const float4*)&pg_s[cc][kx << 3];
                float4 v1 = *(const float4*)&pg_s[cc][(kx << 3) + 4];
                S0[0] += a.x * v0.x; S0[1] += a.x * v0.y;
                S0[2] += a.x * v0.z; S0[3] += a.x * v0.w;
                S0[4] += a.x * v1.x; S0[5] += a.x * v1.y;
                S0[6] += a.x * v1.z; S0[7] += a.x * v1.w;
                S1[0] += a.y * v0.x; S1[1] += a.y * v0.y;
                S1[2] += a.y * v0.z; S1[3] += a.y * v0.w;
                S1[4] += a.y * v1.x; S1[5] += a.y * v1.y;
                S1[6] += a.y * v1.z; S1[7] += a.y * v1.w;
            }
        }
        // tile row-max across the 16 kx lanes
        float m0 = S0[0], m1 = S1[0];
        #pragma unroll
        for (int j = 1; j < 8; j++) { m0 = fmaxf(m0, S0[j]); m1 = fmaxf(m1, S1[j]); }
        #pragma unroll
        for (int off = 1; off < 16; off <<= 1) {
            m0 = fmaxf(m0, __shfl_xor(m0, off));
            m1 = fmaxf(m1, __shfl_xor(m1, off));
        }
        if (kx == 0) {
            float mo = row_m[2 * qy];     float mn = fmaxf(mo, m0);
            row_a[2 * qy] = __expf(mo - mn); row_m[2 * qy] = mn;
            mo = row_m[2 * qy + 1];       mn = fmaxf(mo, m1);
            row_a[2 * qy + 1] = __expf(mo - mn); row_m[2 * qy + 1] = mn;
        }
        __syncthreads();
        float mn0 = row_m[2 * qy], mn1 = row_m[2 * qy + 1];
        float p0[8], p1[8];
        float ps0 = 0.0f, ps1 = 0.0f;
        #pragma unroll
        for (int j = 0; j < 8; j++) {
            p0[j] = __expf(S0[j] - mn0); ps0 += p0[j];
            p1[j] = __expf(S1[j] - mn1); ps1 += p1[j];
        }
        *(float4*)&p_s[2 * qy][kx << 3]           = make_float4(p0[0], p0[1], p0[2], p0[3]);
        *(float4*)&p_s[2 * qy][(kx << 3) + 4]     = make_float4(p0[4], p0[5], p0[6], p0[7]);
        *(float4*)&p_s[2 * qy + 1][kx << 3]       = make_float4(p1[0], p1[1], p1[2], p1[3]);
        *(float4*)&p_s[2 * qy + 1][(kx << 3) + 4] = make_float4(p1[4], p1[5], p1[6], p1[7]);
        #pragma unroll
        for (int off = 1; off < 16; off <<= 1) {
            ps0 += __shfl_xor(ps0, off);
            ps1 += __shfl_xor(ps1, off);
        }
        if (kx == 0) {
            row_l[2 * qy]     = row_l[2 * qy]     * row_a[2 * qy]     + ps0;
            row_l[2 * qy + 1] = row_l[2 * qy + 1] * row_a[2 * qy + 1] + ps1;
        }
        // rescale O (row_a stable until next ktile's write, which is barrier-separated)
        float a0 = row_a[2 * qy], a1 = row_a[2 * qy + 1];
        #pragma unroll
        for (int j = 0; j < 16; j++) { O0[j] *= a0; O1[j] *= a1; }

        const float* ghb = gbuf + (size_t)b * CI * KLEN + kt * 128;
        for (int ch = 0; ch < 8; ch++) {
            __syncthreads();   // also makes p_s / row_l writes visible
            #pragma unroll
            for (int ii = 0; ii < 4; ii++) {
                int fid = t + 256 * ii;
                int row = fid >> 5, col = (fid & 31) << 2;
                *(float4*)&pg_s[row][col] =
                    *(const float4*)(ghb + (size_t)(ch * 32 + row) * KLEN + col);
            }
            __syncthreads();
            #pragma unroll
            for (int kk = 0; kk < 32; kk++) {
                float4 pa = *(const float4*)&p_s[2 * qy][kk << 2];
                float4 pb = *(const float4*)&p_s[2 * qy + 1][kk << 2];
                float4 ga = *(const float4*)&pg_s[cg][kk << 2];
                float4 gb = *(const float4*)&pg_s[cg + 16][kk << 2];
                O0[2 * ch]     += pa.x * ga.x + pa.y * ga.y + pa.z * ga.z + pa.w * ga.w;
                O1[2 * ch]     += pb.x * ga.x + pb.y * ga.y + pb.z * ga.z + pb.w * ga.w;
                O0[2 * ch + 1] += pa.x * gb.x + pa.y * gb.y + pa.z * gb.z + pa.w * gb.w;
                O1[2 * ch + 1] += pb.x * gb.x + pb.y * gb.y + pb.z * gb.z + pb.w * gb.w;
            }
        }
    }

    float li0 = 1.0f / row_l[2 * qy];
    float li1 = 1.0f / row_l[2 * qy + 1];
    __syncthreads();
    #pragma unroll
    for (int j = 0; j < 16; j++) {
        th_s[cg + 16 * j][2 * qy]     = O0[j] * li0;
        th_s[cg + 16 * j][2 * qy + 1] = O1[j] * li1;
    }
    __syncthreads();
    float* yb = y + (size_t)b * CI * LEN + q0;
    #pragma unroll
    for (int ii = 0; ii < 8; ii++) {
        int fid = t + 256 * ii;
        int row = fid >> 3, col = (fid & 7) << 2;
        *(float4*)(yb + (size_t)row * LEN + col) = *(const float4*)&th_s[row][col];
    }
}

// ---------------------------------------------------------------------------
// Kernel 3: z = wz_w . y + wz_b  (written into d_out), plus BN partial sums.
// Grid: (L/64, C/64, B)
// ---------------------------------------------------------------------------
__global__ __launch_bounds__(256) void zgemm_kernel(
    const float* __restrict__ y, const float* __restrict__ W,
    const float* __restrict__ Bs, float* __restrict__ z,
    float* __restrict__ bns, float* __restrict__ bnq)
{
    __shared__ float ys[32][68];
    __shared__ float wt[32][68];

    const int b  = blockIdx.z;
    const int orow0 = blockIdx.y * 64;
    const int l0 = blockIdx.x * 64;
    const int t  = threadIdx.x;
    const int ty = t >> 4, tx = t & 15;

    float acc[4][4] = {};
    const float* yb = y + (size_t)b * CI * LEN + l0;

    for (int c0 = 0; c0 < CI; c0 += 32) {
        __syncthreads();
        #pragma unroll
        for (int ii = 0; ii < 2; ii++) {
            int fid = t + 256 * ii;
            int row = fid >> 4, col = (fid & 15) << 2;
            *(float4*)&ys[row][col] =
                *(const float4*)(yb + (size_t)(c0 + row) * LEN + col);
        }
        #pragma unroll
        for (int ii = 0; ii < 2; ii++) {
            int fid = t + 256 * ii;
            int o = fid >> 3, c4 = (fid & 7) << 2;
            float4 v = *(const float4*)(W + (size_t)(orow0 + o) * CI + c0 + c4);
            wt[c4 + 0][o] = v.x; wt[c4 + 1][o] = v.y;
            wt[c4 + 2][o] = v.z; wt[c4 + 3][o] = v.w;
        }
        __syncthreads();
        #pragma unroll
        for (int k = 0; k < 32; k++) {
            float4 a  = *(const float4*)&wt[k][ty << 2];
            float4 bb = *(const float4*)&ys[k][tx << 2];
            acc[0][0] += a.x * bb.x; acc[0][1] += a.x * bb.y;
            acc[0][2] += a.x * bb.z; acc[0][3] += a.x * bb.w;
            acc[1][0] += a.y * bb.x; acc[1][1] += a.y * bb.y;
            acc[1][2] += a.y * bb.z; acc[1][3] += a.y * bb.w;
            acc[2][0] += a.z * bb.x; acc[2][1] += a.z * bb.y;
            acc[2][2] += a.z * bb.z; acc[2][3] += a.z * bb.w;
            acc[3][0] += a.w * bb.x; acc[3][1] += a.w * bb.y;
            acc[3][2] += a.w * bb.z; acc[3][3] += a.w * bb.w;
        }
    }

    #pragma unroll
    for (int u = 0; u < 4; u++) {
        int o = orow0 + (ty << 2) + u;
        float bias = Bs[o];
        float4 v = make_float4(acc[u][0] + bias, acc[u][1] + bias,
                               acc[u][2] + bias, acc[u][3] + bias);
        *(float4*)(z + ((size_t)b * CIN + o) * LEN + l0 + (tx << 2)) = v;
        float s  = v.x + v.y + v.z + v.w;
        float s2 = v.x * v.x + v.y * v.y + v.z * v.z + v.w * v.w;
        #pragma unroll
        for (int off = 1; off < 16; off <<= 1) {
            s  += __shfl_xor(s,  off);
            s2 += __shfl_xor(s2, off);
        }
        if (tx == 0) {
            atomicAdd(&bns[o], s);
            atomicAdd(&bnq[o], s2);
        }
    }
}

// ---------------------------------------------------------------------------
// Kernel 4: BN normalize (training-mode batch stats, biased var) + residual.
// In-place on d_out (z lives there).
// ---------------------------------------------------------------------------
__global__ __launch_bounds__(256) void bn_kernel(
    float* __restrict__ z, const float* __restrict__ x,
    const float* __restrict__ bns, const float* __restrict__ bnq,
    const float* __restrict__ gamma, const float* __restrict__ beta)
{
    size_t i4 = (size_t)blockIdx.x * 256 + threadIdx.x;   // float4 index
    size_t base = i4 << 2;
    int c = (int)((base >> 12) & (CIN - 1));
    const float invn = 1.0f / (BATCH * LEN);
    float mean = bns[c] * invn;
    float var  = bnq[c] * invn - mean * mean;
    float sc = gamma[c] * rsqrtf(var + 1e-5f);
    float sh = beta[c] - mean * sc;
    float4 zv = *(const float4*)(z + base);
    float4 xv = *(const float4*)(x + base);
    float4 o;
    o.x = zv.x * sc + sh + xv.x;
    o.y = zv.y * sc + sh + xv.y;
    o.z = zv.z * sc + sh + xv.z;
    o.w = zv.w * sc + sh + xv.w;
    *(float4*)(z + base) = o;
}

// ---------------------------------------------------------------------------
extern "C" void kernel_launch(void* const* d_in, const int* in_sizes, int n_in,
                              void* d_out, int out_size, void* d_ws, size_t ws_size,
                              hipStream_t stream)
{
    const float* x     = (const float*)d_in[0];
    const float* tw    = (const float*)d_in[1];
    const float* tb    = (const float*)d_in[2];
    const float* pw    = (const float*)d_in[3];
    const float* pb    = (const float*)d_in[4];
    const float* gw    = (const float*)d_in[5];
    const float* gb    = (const float*)d_in[6];
    const float* wzw   = (const float*)d_in[7];
    const float* wzb   = (const float*)d_in[8];
    const float* gamma = (const float*)d_in[9];
    const float* beta  = (const float*)d_in[10];

    float* out = (float*)d_out;
    float* ws  = (float*)d_ws;

    float* theta = ws;                                   // 8M floats
    float* phi   = theta + (size_t)BATCH * CI * LEN;     // 4M floats
    float* g     = phi   + (size_t)BATCH * CI * KLEN;    // 4M floats
    float* ybuf  = g     + (size_t)BATCH * CI * KLEN;    // 8M floats
    float* bns   = ybuf  + (size_t)BATCH * CI * LEN;     // 512
    float* bnq   = bns + CIN;                            // 512

    hipMemsetAsync(bns, 0, 2 * CIN * sizeof(float), stream);

    proj_kernel<<<dim3(LEN / 64, 12, BATCH), 256, 0, stream>>>(
        x, tw, tb, pw, pb, gw, gb, theta, phi, g);

    attn_kernel<<<dim3(LEN / 32, BATCH), 256, 0, stream>>>(theta, phi, g, ybuf);

    zgemm_kernel<<<dim3(LEN / 64, CIN / 64, BATCH), 256, 0, stream>>>(
        ybuf, wzw, wzb, out, bns, bnq);

    bn_kernel<<<(BATCH * CIN * LEN) / 4 / 256, 256, 0, stream>>>(
        out, x, bns, bnq, gamma, beta);
}

// Round 2
// 686.165 us; speedup vs baseline: 4.0668x; 4.0668x over previous
//
#include <hip/hip_runtime.h>

// Problem constants: B=8, C=512, L=4096, Ci=256, K=L/2=2048
#define BATCH 8
#define CIN   512
#define LEN   4096
#define CI    256
#define KLEN  2048

typedef _Float16 half_t;
typedef _Float16 half2_t __attribute__((ext_vector_type(2)));
typedef _Float16 half4_t __attribute__((ext_vector_type(4)));
typedef _Float16 half8_t __attribute__((ext_vector_type(8)));
typedef float    floatx4 __attribute__((ext_vector_type(4)));

// async global->LDS 16B copy (wave-uniform LDS base + lane*16 pattern required)
__device__ __forceinline__ void async16(void* lds_dst, const void* g_src) {
    __builtin_amdgcn_global_load_lds(
        (const __attribute__((address_space(1))) unsigned int*)g_src,
        (__attribute__((address_space(3))) unsigned int*)lds_dst,
        16, 0, 0);
}

// ---------------------------------------------------------------------------
// Kernel 1: theta/phi/g projections (fp32 GEMM core, fp16 outputs in MFMA-
// friendly layouts).  thetaT[b][l][c], phiT[b][k][c] (maxpooled), g[b][c][k].
// Grid: (L/64, 12, B). blockIdx.y: 0-3 theta rows, 4-7 phi, 8-11 g.
// ---------------------------------------------------------------------------
__global__ __launch_bounds__(256) void proj_kernel(
    const float* __restrict__ x,
    const float* __restrict__ tw, const float* __restrict__ tb,
    const float* __restrict__ pw, const float* __restrict__ pb,
    const float* __restrict__ gw, const float* __restrict__ gb,
    half_t* __restrict__ thetaT, half_t* __restrict__ phiT,
    half_t* __restrict__ gH)
{
    __shared__ float xs[32][68];
    __shared__ float wt[32][68];

    const int b  = blockIdx.z;
    const int ot = blockIdx.y;
    const int l0 = blockIdx.x * 64;
    const int which = ot >> 2;
    const int orow0 = (ot & 3) * 64;

    const float* W  = (which == 0) ? tw : ((which == 1) ? pw : gw);
    const float* Bs = (which == 0) ? tb : ((which == 1) ? pb : gb);

    const int t  = threadIdx.x;
    const int ty = t >> 4;
    const int tx = t & 15;

    float acc[4][4] = {};
    const float* xb = x + (size_t)b * CIN * LEN + l0;

    for (int c0 = 0; c0 < CIN; c0 += 32) {
        __syncthreads();
        #pragma unroll
        for (int ii = 0; ii < 2; ii++) {
            int fid = t + 256 * ii;
            int row = fid >> 4, col = (fid & 15) << 2;
            *(float4*)&xs[row][col] =
                *(const float4*)(xb + (size_t)(c0 + row) * LEN + col);
        }
        #pragma unroll
        for (int ii = 0; ii < 2; ii++) {
            int fid = t + 256 * ii;
            int o = fid >> 3, c4 = (fid & 7) << 2;
            float4 v = *(const float4*)(W + (size_t)(orow0 + o) * CIN + c0 + c4);
            wt[c4 + 0][o] = v.x; wt[c4 + 1][o] = v.y;
            wt[c4 + 2][o] = v.z; wt[c4 + 3][o] = v.w;
        }
        __syncthreads();
        #pragma unroll
        for (int k = 0; k < 32; k++) {
            float4 a  = *(const float4*)&wt[k][ty << 2];
            float4 bb = *(const float4*)&xs[k][tx << 2];
            acc[0][0] += a.x * bb.x; acc[0][1] += a.x * bb.y;
            acc[0][2] += a.x * bb.z; acc[0][3] += a.x * bb.w;
            acc[1][0] += a.y * bb.x; acc[1][1] += a.y * bb.y;
            acc[1][2] += a.y * bb.z; acc[1][3] += a.y * bb.w;
            acc[2][0] += a.z * bb.x; acc[2][1] += a.z * bb.y;
            acc[2][2] += a.z * bb.z; acc[2][3] += a.z * bb.w;
            acc[3][0] += a.w * bb.x; acc[3][1] += a.w * bb.y;
            acc[3][2] += a.w * bb.z; acc[3][3] += a.w * bb.w;
        }
    }

    const int ob = orow0 + (ty << 2);
    const float b0 = Bs[ob + 0], b1 = Bs[ob + 1],
                b2 = Bs[ob + 2], b3 = Bs[ob + 3];

    if (which == 0) {
        // thetaT[b][l][c]: per l, 4 consecutive channels -> 8B store
        #pragma unroll
        for (int i = 0; i < 4; i++) {
            int l = l0 + (tx << 2) + i;
            half4_t v = { (half_t)(acc[0][i] + b0), (half_t)(acc[1][i] + b1),
                          (half_t)(acc[2][i] + b2), (half_t)(acc[3][i] + b3) };
            *(half4_t*)(thetaT + ((size_t)b * LEN + l) * CI + ob) = v;
        }
    } else if (which == 1) {
        // phiT[b][k][c], maxpool over l pairs
        #pragma unroll
        for (int i2 = 0; i2 < 2; i2++) {
            int k = (l0 >> 1) + (tx << 1) + i2;
            half4_t v = {
                (half_t)(fmaxf(acc[0][2*i2], acc[0][2*i2+1]) + b0),
                (half_t)(fmaxf(acc[1][2*i2], acc[1][2*i2+1]) + b1),
                (half_t)(fmaxf(acc[2][2*i2], acc[2][2*i2+1]) + b2),
                (half_t)(fmaxf(acc[3][2*i2], acc[3][2*i2+1]) + b3) };
            *(half4_t*)(phiT + ((size_t)b * KLEN + k) * CI + ob) = v;
        }
    } else {
        // g[b][c][k], maxpool over l pairs
        const float bb[4] = { b0, b1, b2, b3 };
        #pragma unroll
        for (int u = 0; u < 4; u++) {
            half2_t v = { (half_t)(fmaxf(acc[u][0], acc[u][1]) + bb[u]),
                          (half_t)(fmaxf(acc[u][2], acc[u][3]) + bb[u]) };
            *(half2_t*)(gH + ((size_t)b * CI + ob + u) * KLEN
                           + (l0 >> 1) + (tx << 1)) = v;
        }
    }
}

// ---------------------------------------------------------------------------
// Kernel 2: MFMA flash attention (fp16 in, fp32 accum).
//  S'[k][q] = sum_c phi[c,k] theta[c,q]  via mfma_f32_16x16x32_f16 (m=k,n=q)
//  P = exp(S'-m) lands in C-layout == B-operand layout of 16x16x16_f16
//  O[c][q] += g-frag * P  via mfma_f32_16x16x16f16
// Block: 64 queries, 4 waves (wave-private 16q). K-tile 64, staged via
// global_load_lds into XOR-swizzled LDS (pow2 pitch, <=2-way bank alias).
// Grid: (B=8, L/64) so linear%8==b pins each batch's phi/g to one XCD's L2.
// ---------------------------------------------------------------------------
__global__ __launch_bounds__(256, 2) void attn_kernel(
    const half_t* __restrict__ thetaT,   // [B][L][CI]
    const half_t* __restrict__ phiT,     // [B][KLEN][CI]
    const half_t* __restrict__ gH,       // [B][CI][KLEN]
    float* __restrict__ y)               // [B][CI][LEN]
{
    __shared__ half_t phi_s[64 * 256];   // 64 rows x 512B, granule-swizzled
    __shared__ half_t g_s[256 * 64];     // 256 rows x 128B, granule-swizzled

    const int b    = blockIdx.x;
    const int q0   = blockIdx.y * 64;
    const int t    = threadIdx.x;
    const int w    = t >> 6;
    const int lane = t & 63;
    const int ln   = lane & 15;
    const int quad = lane >> 4;
    const int qw   = q0 + w * 16;        // this wave's q base

    // ---- preload theta B-fragments (whole 256-c reduction, 8 chunks) ----
    half8_t thf[8];
    {
        const half_t* thb = thetaT + ((size_t)b * LEN + qw + ln) * CI + quad * 8;
        #pragma unroll
        for (int ch = 0; ch < 8; ch++)
            thf[ch] = *(const half8_t*)(thb + ch * 32);
    }

    floatx4 O[16];
    #pragma unroll
    for (int i = 0; i < 16; i++) O[i] = (floatx4)(0.0f);
    float m_run = -3.0e38f;
    float l_run = 0.0f;

    const half_t* phib = phiT + (size_t)b * KLEN * CI;
    const half_t* gb   = gH   + (size_t)b * CI * KLEN;

    for (int kt = 0; kt < KLEN; kt += 64) {
        __syncthreads();   // previous iteration's LDS reads complete
        // ---- stage phi tile (32KB) ----
        #pragma unroll
        for (int it = 0; it < 8; it++) {
            int o   = t * 16 + it * 4096;          // LDS byte offset
            int row = o >> 9;                      // 512B rows
            int gsw = (o >> 4) & 31;
            int gsrc = gsw ^ (row & 31);
            async16(&phi_s[o >> 1],
                    phib + (size_t)(kt + row) * CI + gsrc * 8);
        }
        // ---- stage g tile (32KB) ----
        #pragma unroll
        for (int it = 0; it < 8; it++) {
            int o   = t * 16 + it * 4096;
            int row = o >> 7;                      // 128B rows
            int gsw = (o >> 4) & 7;
            int gsrc = gsw ^ (row & 7);
            async16(&g_s[o >> 1],
                    gb + (size_t)row * KLEN + kt + gsrc * 8);
        }
        __syncthreads();   // drains vmcnt -> tiles visible

        // ---- S' = phi-tile^T x theta  (4 k-subtiles x 8 c-chunks) ----
        floatx4 S[4];
        #pragma unroll
        for (int k16 = 0; k16 < 4; k16++) S[k16] = (floatx4)(0.0f);
        #pragma unroll
        for (int k16 = 0; k16 < 4; k16++) {
            int row = k16 * 16 + ln;
            int rs  = row & 31;
            #pragma unroll
            for (int ch = 0; ch < 8; ch++) {
                int gr = (ch * 4 + quad) ^ rs;
                half8_t a = *(const half8_t*)&phi_s[(row << 8) + gr * 8];
                S[k16] = __builtin_amdgcn_mfma_f32_16x16x32_f16(
                             a, thf[ch], S[k16], 0, 0, 0);
            }
        }

        // ---- online softmax (per-lane state for q = lane&15) ----
        float tmax = S[0][0];
        #pragma unroll
        for (int k16 = 0; k16 < 4; k16++)
            #pragma unroll
            for (int r = 0; r < 4; r++) tmax = fmaxf(tmax, S[k16][r]);
        tmax = fmaxf(tmax, __shfl_xor(tmax, 16));
        tmax = fmaxf(tmax, __shfl_xor(tmax, 32));
        float m_new = fmaxf(m_run, tmax);
        float alpha = __expf(m_run - m_new);
        m_run = m_new;
        l_run *= alpha;

        half4_t P[4];
        #pragma unroll
        for (int k16 = 0; k16 < 4; k16++) {
            float p0 = __expf(S[k16][0] - m_new);
            float p1 = __expf(S[k16][1] - m_new);
            float p2 = __expf(S[k16][2] - m_new);
            float p3 = __expf(S[k16][3] - m_new);
            l_run += (p0 + p1) + (p2 + p3);
            half4_t pv = { (half_t)p0, (half_t)p1, (half_t)p2, (half_t)p3 };
            P[k16] = pv;
        }
        #pragma unroll
        for (int i = 0; i < 16; i++) O[i] *= alpha;

        // ---- PV: O[c][q] += g * P  (16 c-subtiles x 4 k-subtiles) ----
        const int lnm = ln & 7;
        #pragma unroll
        for (int k16 = 0; k16 < 4; k16++) {
            int gr   = (2 * k16 + (quad >> 1)) ^ lnm;
            int coff = gr * 8 + (quad & 1) * 4;    // half index within row
            #pragma unroll
            for (int csub = 0; csub < 16; csub++) {
                int row = csub * 16 + ln;
                half4_t a = *(const half4_t*)&g_s[(row << 6) + coff];
                O[csub] = __builtin_amdgcn_mfma_f32_16x16x16f16(
                              a, P[k16], O[csub], 0, 0, 0);
            }
        }
    }

    // ---- finalize: l across quads, normalize, write y[b][c][q] fp32 ----
    l_run += __shfl_xor(l_run, 16);
    l_run += __shfl_xor(l_run, 32);
    float inv = 1.0f / l_run;
    float* yb = y + (size_t)b * CI * LEN + qw + ln;
    #pragma unroll
    for (int csub = 0; csub < 16; csub++) {
        #pragma unroll
        for (int r = 0; r < 4; r++) {
            int c = csub * 16 + quad * 4 + r;
            yb[(size_t)c * LEN] = O[csub][r] * inv;
        }
    }
}

// ---------------------------------------------------------------------------
// Kernel 3: z = wz_w . y + wz_b (into d_out) + BN partial sums.
// ---------------------------------------------------------------------------
__global__ __launch_bounds__(256) void zgemm_kernel(
    const float* __restrict__ y, const float* __restrict__ W,
    const float* __restrict__ Bs, float* __restrict__ z,
    float* __restrict__ bns, float* __restrict__ bnq)
{
    __shared__ float ys[32][68];
    __shared__ float wt[32][68];

    const int b  = blockIdx.z;
    const int orow0 = blockIdx.y * 64;
    const int l0 = blockIdx.x * 64;
    const int t  = threadIdx.x;
    const int ty = t >> 4, tx = t & 15;

    float acc[4][4] = {};
    const float* yb = y + (size_t)b * CI * LEN + l0;

    for (int c0 = 0; c0 < CI; c0 += 32) {
        __syncthreads();
        #pragma unroll
        for (int ii = 0; ii < 2; ii++) {
            int fid = t + 256 * ii;
            int row = fid >> 4, col = (fid & 15) << 2;
            *(float4*)&ys[row][col] =
                *(const float4*)(yb + (size_t)(c0 + row) * LEN + col);
        }
        #pragma unroll
        for (int ii = 0; ii < 2; ii++) {
            int fid = t + 256 * ii;
            int o = fid >> 3, c4 = (fid & 7) << 2;
            float4 v = *(const float4*)(W + (size_t)(orow0 + o) * CI + c0 + c4);
            wt[c4 + 0][o] = v.x; wt[c4 + 1][o] = v.y;
            wt[c4 + 2][o] = v.z; wt[c4 + 3][o] = v.w;
        }
        __syncthreads();
        #pragma unroll
        for (int k = 0; k < 32; k++) {
            float4 a  = *(const float4*)&wt[k][ty << 2];
            float4 bb = *(const float4*)&ys[k][tx << 2];
            acc[0][0] += a.x * bb.x; acc[0][1] += a.x * bb.y;
            acc[0][2] += a.x * bb.z; acc[0][3] += a.x * bb.w;
            acc[1][0] += a.y * bb.x; acc[1][1] += a.y * bb.y;
            acc[1][2] += a.y * bb.z; acc[1][3] += a.y * bb.w;
            acc[2][0] += a.z * bb.x; acc[2][1] += a.z * bb.y;
            acc[2][2] += a.z * bb.z; acc[2][3] += a.z * bb.w;
            acc[3][0] += a.w * bb.x; acc[3][1] += a.w * bb.y;
            acc[3][2] += a.w * bb.z; acc[3][3] += a.w * bb.w;
        }
    }

    #pragma unroll
    for (int u = 0; u < 4; u++) {
        int o = orow0 + (ty << 2) + u;
        float bias = Bs[o];
        float4 v = make_float4(acc[u][0] + bias, acc[u][1] + bias,
                               acc[u][2] + bias, acc[u][3] + bias);
        *(float4*)(z + ((size_t)b * CIN + o) * LEN + l0 + (tx << 2)) = v;
        float s  = v.x + v.y + v.z + v.w;
        float s2 = v.x * v.x + v.y * v.y + v.z * v.z + v.w * v.w;
        #pragma unroll
        for (int off = 1; off < 16; off <<= 1) {
            s  += __shfl_xor(s,  off);
            s2 += __shfl_xor(s2, off);
        }
        if (tx == 0) {
            atomicAdd(&bns[o], s);
            atomicAdd(&bnq[o], s2);
        }
    }
}

// ---------------------------------------------------------------------------
// Kernel 4: BN normalize (batch stats, biased var) + residual, in-place.
// ---------------------------------------------------------------------------
__global__ __launch_bounds__(256) void bn_kernel(
    float* __restrict__ z, const float* __restrict__ x,
    const float* __restrict__ bns, const float* __restrict__ bnq,
    const float* __restrict__ gamma, const float* __restrict__ beta)
{
    size_t i4 = (size_t)blockIdx.x * 256 + threadIdx.x;
    size_t base = i4 << 2;
    int c = (int)((base >> 12) & (CIN - 1));
    const float invn = 1.0f / (BATCH * LEN);
    float mean = bns[c] * invn;
    float var  = bnq[c] * invn - mean * mean;
    float sc = gamma[c] * rsqrtf(var + 1e-5f);
    float sh = beta[c] - mean * sc;
    float4 zv = *(const float4*)(z + base);
    float4 xv = *(const float4*)(x + base);
    float4 o;
    o.x = zv.x * sc + sh + xv.x;
    o.y = zv.y * sc + sh + xv.y;
    o.z = zv.z * sc + sh + xv.z;
    o.w = zv.w * sc + sh + xv.w;
    *(float4*)(z + base) = o;
}

// ---------------------------------------------------------------------------
extern "C" void kernel_launch(void* const* d_in, const int* in_sizes, int n_in,
                              void* d_out, int out_size, void* d_ws, size_t ws_size,
                              hipStream_t stream)
{
    const float* x     = (const float*)d_in[0];
    const float* tw    = (const float*)d_in[1];
    const float* tb    = (const float*)d_in[2];
    const float* pw    = (const float*)d_in[3];
    const float* pb    = (const float*)d_in[4];
    const float* gw    = (const float*)d_in[5];
    const float* gb    = (const float*)d_in[6];
    const float* wzw   = (const float*)d_in[7];
    const float* wzb   = (const float*)d_in[8];
    const float* gamma = (const float*)d_in[9];
    const float* beta  = (const float*)d_in[10];

    float* out = (float*)d_out;

    half_t* thetaT = (half_t*)d_ws;                             // 16 MB
    half_t* phiT   = thetaT + (size_t)BATCH * LEN * CI;         //  8 MB
    half_t* gH     = phiT   + (size_t)BATCH * KLEN * CI;        //  8 MB
    float*  ybuf   = (float*)(gH + (size_t)BATCH * CI * KLEN);  // 32 MB
    float*  bns    = ybuf + (size_t)BATCH * CI * LEN;
    float*  bnq    = bns + CIN;

    hipMemsetAsync(bns, 0, 2 * CIN * sizeof(float), stream);

    proj_kernel<<<dim3(LEN / 64, 12, BATCH), 256, 0, stream>>>(
        x, tw, tb, pw, pb, gw, gb, thetaT, phiT, gH);

    attn_kernel<<<dim3(BATCH, LEN / 64), 256, 0, stream>>>(
        thetaT, phiT, gH, ybuf);

    zgemm_kernel<<<dim3(LEN / 64, CIN / 64, BATCH), 256, 0, stream>>>(
        ybuf, wzw, wzb, out, bns, bnq);

    bn_kernel<<<(BATCH * CIN * LEN) / 4 / 256, 256, 0, stream>>>(
        out, x, bns, bnq, gamma, beta);
}

// Round 3
// 336.761 us; speedup vs baseline: 8.2863x; 2.0375x over previous
//
#include <hip/hip_runtime.h>

// Problem constants: B=8, C=512, L=4096, Ci=256, K=L/2=2048
#define BATCH 8
#define CIN   512
#define LEN   4096
#define CI    256
#define KLEN  2048

typedef _Float16 half_t;
typedef _Float16 half2_t __attribute__((ext_vector_type(2)));
typedef _Float16 half4_t __attribute__((ext_vector_type(4)));
typedef _Float16 half8_t __attribute__((ext_vector_type(8)));
typedef float    floatx4 __attribute__((ext_vector_type(4)));

// async global->LDS 16B copy (wave-uniform LDS base + lane*16 pattern required)
__device__ __forceinline__ void async16(void* lds_dst, const void* g_src) {
    __builtin_amdgcn_global_load_lds(
        (const __attribute__((address_space(1))) unsigned int*)g_src,
        (__attribute__((address_space(3))) unsigned int*)lds_dst,
        16, 0, 0);
}

// ---------------------------------------------------------------------------
// Kernel A: convert+transpose x[b][c][l] f32 -> xhT[b][l][c] f16.
// 64x64 tiles through LDS. Grid (L/64, CIN/64, B).
// ---------------------------------------------------------------------------
__global__ __launch_bounds__(256) void xpose_kernel(
    const float* __restrict__ x, half_t* __restrict__ xhT)
{
    __shared__ half_t tile[64][72];   // [l][c], 144B rows (16B-aligned)
    const int b = blockIdx.z, c0 = blockIdx.y * 64, l0 = blockIdx.x * 64;
    const int t = threadIdx.x;
    #pragma unroll
    for (int i = 0; i < 4; i++) {
        int fid = t + 256 * i;                 // 1024 float4 reads
        int c = fid >> 4, lb = (fid & 15) << 2;
        float4 v = *(const float4*)(x + ((size_t)b * CIN + c0 + c) * LEN + l0 + lb);
        tile[lb + 0][c] = (half_t)v.x;
        tile[lb + 1][c] = (half_t)v.y;
        tile[lb + 2][c] = (half_t)v.z;
        tile[lb + 3][c] = (half_t)v.w;
    }
    __syncthreads();
    #pragma unroll
    for (int i = 0; i < 2; i++) {
        int fid = t + 256 * i;                 // 512 half8 writes
        int l = fid >> 3, cb = (fid & 7) << 3;
        half8_t v = *(const half8_t*)&tile[l][cb];
        *(half8_t*)(xhT + ((size_t)b * LEN + l0 + l) * CIN + c0 + cb) = v;
    }
}

// ---------------------------------------------------------------------------
// Kernel B: convert weights to fp16. Wh[768][512] = {theta,phi,g} stacked,
// wzh[512][256]. Grid 256x256, 8 elements/thread.
// ---------------------------------------------------------------------------
__global__ __launch_bounds__(256) void wconv_kernel(
    const float* __restrict__ tw, const float* __restrict__ pw,
    const float* __restrict__ gw, const float* __restrict__ wzw,
    half_t* __restrict__ Wh, half_t* __restrict__ wzh)
{
    size_t base = ((size_t)blockIdx.x * 256 + threadIdx.x) * 8;
    const float* src;
    half_t* dst;
    if (base < 768 * 512) {
        size_t o = base >> 9, c = base & 511;
        src = (o < 256 ? tw + o * 512
                       : (o < 512 ? pw + (o - 256) * 512 : gw + (o - 512) * 512)) + c;
        dst = Wh + base;
    } else {
        size_t off = base - 768 * 512;
        src = wzw + off;
        dst = wzh + off;
    }
    float4 a = *(const float4*)src, b2 = *(const float4*)(src + 4);
    half8_t h = { (half_t)a.x, (half_t)a.y, (half_t)a.z, (half_t)a.w,
                  (half_t)b2.x, (half_t)b2.y, (half_t)b2.z, (half_t)b2.w };
    *(half8_t*)dst = h;
}

// ---------------------------------------------------------------------------
// Kernel 1: MFMA projection GEMM.  out[o,l] = sum_c Wh[o,c] xhT[l,c], o=0..767
// covers theta(0-255), phi(256-511), g(512-767); maxpool fused for phi/g.
// 128x128 tile, 4 waves (64x64 each, 4x4 16x16x32 subtiles), BK=32.
// C-layout: col=l (ln), row=o (quad*4+reg). Grid (L/128, 6, B).
// ---------------------------------------------------------------------------
__global__ __launch_bounds__(256, 2) void projmm_kernel(
    const half_t* __restrict__ xhT, const half_t* __restrict__ Wh,
    const float* __restrict__ tb, const float* __restrict__ pb,
    const float* __restrict__ gb,
    half_t* __restrict__ thetaT, half_t* __restrict__ phiT,
    half_t* __restrict__ gH)
{
    __shared__ half_t wsm[128 * 32];   // W tile [o][c], 64B rows
    __shared__ half_t xsm[128 * 32];   // x tile [l][c], 64B rows

    const int b  = blockIdx.z;
    const int o0 = blockIdx.y * 128;
    const int l0 = blockIdx.x * 128;
    const int t  = threadIdx.x;
    const int lane = t & 63, w = t >> 6;
    const int ln = lane & 15, quad = lane >> 4;
    const int wm = w >> 1, wn = w & 1;

    floatx4 acc[4][4];
    #pragma unroll
    for (int mi = 0; mi < 4; mi++)
        #pragma unroll
        for (int nj = 0; nj < 4; nj++) acc[mi][nj] = (floatx4)(0.0f);

    const half_t* Wb = Wh + (size_t)o0 * 512;
    const half_t* xb = xhT + ((size_t)b * LEN + l0) * CIN;

    for (int k0 = 0; k0 < 512; k0 += 32) {
        __syncthreads();
        #pragma unroll
        for (int it = 0; it < 2; it++) {
            int off = t * 16 + it * 4096;       // LDS byte offset
            int row = off >> 6, c8 = (off >> 4) & 3;
            async16(&wsm[off >> 1], Wb + (size_t)row * 512 + k0 + c8 * 8);
            async16(&xsm[off >> 1], xb + (size_t)row * CIN + k0 + c8 * 8);
        }
        __syncthreads();
        half8_t af[4], bf[4];
        #pragma unroll
        for (int mi = 0; mi < 4; mi++)
            af[mi] = *(const half8_t*)&wsm[(wm * 64 + mi * 16 + ln) * 32 + quad * 8];
        #pragma unroll
        for (int nj = 0; nj < 4; nj++)
            bf[nj] = *(const half8_t*)&xsm[(wn * 64 + nj * 16 + ln) * 32 + quad * 8];
        #pragma unroll
        for (int mi = 0; mi < 4; mi++)
            #pragma unroll
            for (int nj = 0; nj < 4; nj++)
                acc[mi][nj] = __builtin_amdgcn_mfma_f32_16x16x32_f16(
                                  af[mi], bf[nj], acc[mi][nj], 0, 0, 0);
    }

    const int which = o0 >> 8;          // 0=theta, 1=phi, 2=g
    const int obase = o0 & 255;
    const float* Bp = which == 0 ? tb : (which == 1 ? pb : gb);

    float bias[4][4];
    #pragma unroll
    for (int mi = 0; mi < 4; mi++)
        #pragma unroll
        for (int r = 0; r < 4; r++)
            bias[mi][r] = Bp[obase + wm * 64 + mi * 16 + quad * 4 + r];

    if (which == 0) {
        #pragma unroll
        for (int mi = 0; mi < 4; mi++) {
            int o = obase + wm * 64 + mi * 16 + quad * 4;
            #pragma unroll
            for (int nj = 0; nj < 4; nj++) {
                int l = l0 + wn * 64 + nj * 16 + ln;
                half4_t v = { (half_t)(acc[mi][nj][0] + bias[mi][0]),
                              (half_t)(acc[mi][nj][1] + bias[mi][1]),
                              (half_t)(acc[mi][nj][2] + bias[mi][2]),
                              (half_t)(acc[mi][nj][3] + bias[mi][3]) };
                *(half4_t*)(thetaT + ((size_t)b * LEN + l) * CI + o) = v;
            }
        }
    } else {
        #pragma unroll
        for (int mi = 0; mi < 4; mi++) {
            int o = obase + wm * 64 + mi * 16 + quad * 4;
            #pragma unroll
            for (int nj = 0; nj < 4; nj++) {
                int l = l0 + wn * 64 + nj * 16 + ln;
                float mx[4];
                #pragma unroll
                for (int r = 0; r < 4; r++) {
                    float other = __shfl_xor(acc[mi][nj][r], 1);
                    mx[r] = fmaxf(acc[mi][nj][r], other) + bias[mi][r];
                }
                if ((ln & 1) == 0) {
                    int kk = l >> 1;
                    if (which == 1) {
                        half4_t v = { (half_t)mx[0], (half_t)mx[1],
                                      (half_t)mx[2], (half_t)mx[3] };
                        *(half4_t*)(phiT + ((size_t)b * KLEN + kk) * CI + o) = v;
                    } else {
                        #pragma unroll
                        for (int r = 0; r < 4; r++)
                            gH[((size_t)b * CI + o + r) * KLEN + kk] = (half_t)mx[r];
                    }
                }
            }
        }
    }
}

// ---------------------------------------------------------------------------
// Kernel 2: MFMA flash attention (unchanged core); epilogue now writes fp16
// yhT[b][l][c] for the MFMA zgemm. Grid (B, L/64).
// ---------------------------------------------------------------------------
__global__ __launch_bounds__(256, 2) void attn_kernel(
    const half_t* __restrict__ thetaT,   // [B][L][CI]
    const half_t* __restrict__ phiT,     // [B][KLEN][CI]
    const half_t* __restrict__ gH,       // [B][CI][KLEN]
    half_t* __restrict__ yhT)            // [B][LEN][CI]
{
    __shared__ half_t phi_s[64 * 256];   // 64 rows x 512B, granule-swizzled
    __shared__ half_t g_s[256 * 64];     // 256 rows x 128B, granule-swizzled

    const int b    = blockIdx.x;
    const int q0   = blockIdx.y * 64;
    const int t    = threadIdx.x;
    const int w    = t >> 6;
    const int lane = t & 63;
    const int ln   = lane & 15;
    const int quad = lane >> 4;
    const int qw   = q0 + w * 16;

    half8_t thf[8];
    {
        const half_t* thb = thetaT + ((size_t)b * LEN + qw + ln) * CI + quad * 8;
        #pragma unroll
        for (int ch = 0; ch < 8; ch++)
            thf[ch] = *(const half8_t*)(thb + ch * 32);
    }

    floatx4 O[16];
    #pragma unroll
    for (int i = 0; i < 16; i++) O[i] = (floatx4)(0.0f);
    float m_run = -3.0e38f;
    float l_run = 0.0f;

    const half_t* phib = phiT + (size_t)b * KLEN * CI;
    const half_t* gb   = gH   + (size_t)b * CI * KLEN;

    for (int kt = 0; kt < KLEN; kt += 64) {
        __syncthreads();
        #pragma unroll
        for (int it = 0; it < 8; it++) {
            int o   = t * 16 + it * 4096;
            int row = o >> 9;
            int gsw = (o >> 4) & 31;
            int gsrc = gsw ^ (row & 31);
            async16(&phi_s[o >> 1],
                    phib + (size_t)(kt + row) * CI + gsrc * 8);
        }
        #pragma unroll
        for (int it = 0; it < 8; it++) {
            int o   = t * 16 + it * 4096;
            int row = o >> 7;
            int gsw = (o >> 4) & 7;
            int gsrc = gsw ^ (row & 7);
            async16(&g_s[o >> 1],
                    gb + (size_t)row * KLEN + kt + gsrc * 8);
        }
        __syncthreads();

        floatx4 S[4];
        #pragma unroll
        for (int k16 = 0; k16 < 4; k16++) S[k16] = (floatx4)(0.0f);
        #pragma unroll
        for (int k16 = 0; k16 < 4; k16++) {
            int row = k16 * 16 + ln;
            int rs  = row & 31;
            #pragma unroll
            for (int ch = 0; ch < 8; ch++) {
                int gr = (ch * 4 + quad) ^ rs;
                half8_t a = *(const half8_t*)&phi_s[(row << 8) + gr * 8];
                S[k16] = __builtin_amdgcn_mfma_f32_16x16x32_f16(
                             a, thf[ch], S[k16], 0, 0, 0);
            }
        }

        float tmax = S[0][0];
        #pragma unroll
        for (int k16 = 0; k16 < 4; k16++)
            #pragma unroll
            for (int r = 0; r < 4; r++) tmax = fmaxf(tmax, S[k16][r]);
        tmax = fmaxf(tmax, __shfl_xor(tmax, 16));
        tmax = fmaxf(tmax, __shfl_xor(tmax, 32));
        float m_new = fmaxf(m_run, tmax);
        float alpha = __expf(m_run - m_new);
        m_run = m_new;
        l_run *= alpha;

        half4_t P[4];
        #pragma unroll
        for (int k16 = 0; k16 < 4; k16++) {
            float p0 = __expf(S[k16][0] - m_new);
            float p1 = __expf(S[k16][1] - m_new);
            float p2 = __expf(S[k16][2] - m_new);
            float p3 = __expf(S[k16][3] - m_new);
            l_run += (p0 + p1) + (p2 + p3);
            half4_t pv = { (half_t)p0, (half_t)p1, (half_t)p2, (half_t)p3 };
            P[k16] = pv;
        }
        #pragma unroll
        for (int i = 0; i < 16; i++) O[i] *= alpha;

        const int lnm = ln & 7;
        #pragma unroll
        for (int k16 = 0; k16 < 4; k16++) {
            int gr   = (2 * k16 + (quad >> 1)) ^ lnm;
            int coff = gr * 8 + (quad & 1) * 4;
            #pragma unroll
            for (int csub = 0; csub < 16; csub++) {
                int row = csub * 16 + ln;
                half4_t a = *(const half4_t*)&g_s[(row << 6) + coff];
                O[csub] = __builtin_amdgcn_mfma_f32_16x16x16f16(
                              a, P[k16], O[csub], 0, 0, 0);
            }
        }
    }

    l_run += __shfl_xor(l_run, 16);
    l_run += __shfl_xor(l_run, 32);
    float inv = 1.0f / l_run;
    // write yhT[b][q][c]: per lane fixed q=qw+ln, 16 x half4 at c=csub*16+quad*4
    half_t* yb = yhT + ((size_t)b * LEN + qw + ln) * CI;
    #pragma unroll
    for (int csub = 0; csub < 16; csub++) {
        int c = csub * 16 + quad * 4;
        half4_t v = { (half_t)(O[csub][0] * inv), (half_t)(O[csub][1] * inv),
                      (half_t)(O[csub][2] * inv), (half_t)(O[csub][3] * inv) };
        *(half4_t*)(yb + c) = v;
    }
}

// ---------------------------------------------------------------------------
// Kernel 3: MFMA zgemm. z[o,l] = sum_c wzh[o,c] yhT[l,c] + wz_b, into d_out,
// plus BN partial sums. Orientation m=l, n=o -> float4 stores along l.
// Grid (L/128, 4, B).
// ---------------------------------------------------------------------------
__global__ __launch_bounds__(256, 2) void zmm_kernel(
    const half_t* __restrict__ yhT, const half_t* __restrict__ wzh,
    const float* __restrict__ wzb, float* __restrict__ z,
    float* __restrict__ bns, float* __restrict__ bnq)
{
    __shared__ half_t ysm[128 * 32];   // y tile [l][c]
    __shared__ half_t wsm[128 * 32];   // W tile [o][c]

    const int b  = blockIdx.z;
    const int o0 = blockIdx.y * 128;
    const int l0 = blockIdx.x * 128;
    const int t  = threadIdx.x;
    const int lane = t & 63, w = t >> 6;
    const int ln = lane & 15, quad = lane >> 4;
    const int wm = w >> 1, wn = w & 1;

    floatx4 acc[4][4];
    #pragma unroll
    for (int mi = 0; mi < 4; mi++)
        #pragma unroll
        for (int nj = 0; nj < 4; nj++) acc[mi][nj] = (floatx4)(0.0f);

    const half_t* yb = yhT + ((size_t)b * LEN + l0) * CI;
    const half_t* Wb = wzh + (size_t)o0 * CI;

    for (int k0 = 0; k0 < 256; k0 += 32) {
        __syncthreads();
        #pragma unroll
        for (int it = 0; it < 2; it++) {
            int off = t * 16 + it * 4096;
            int row = off >> 6, c8 = (off >> 4) & 3;
            async16(&ysm[off >> 1], yb + (size_t)row * CI + k0 + c8 * 8);
            async16(&wsm[off >> 1], Wb + (size_t)row * CI + k0 + c8 * 8);
        }
        __syncthreads();
        half8_t af[4], bf[4];
        #pragma unroll
        for (int mi = 0; mi < 4; mi++)
            af[mi] = *(const half8_t*)&ysm[(wm * 64 + mi * 16 + ln) * 32 + quad * 8];
        #pragma unroll
        for (int nj = 0; nj < 4; nj++)
            bf[nj] = *(const half8_t*)&wsm[(wn * 64 + nj * 16 + ln) * 32 + quad * 8];
        #pragma unroll
        for (int mi = 0; mi < 4; mi++)
            #pragma unroll
            for (int nj = 0; nj < 4; nj++)
                acc[mi][nj] = __builtin_amdgcn_mfma_f32_16x16x32_f16(
                                  af[mi], bf[nj], acc[mi][nj], 0, 0, 0);
    }

    // C: row = l = quad*4+r, col = o = ln
    float s[4] = {0, 0, 0, 0}, s2[4] = {0, 0, 0, 0};
    #pragma unroll
    for (int nj = 0; nj < 4; nj++) {
        int o = o0 + wn * 64 + nj * 16 + ln;
        float bo = wzb[o];
        #pragma unroll
        for (int mi = 0; mi < 4; mi++) {
            int l = l0 + wm * 64 + mi * 16 + quad * 4;
            float4 v = make_float4(acc[mi][nj][0] + bo, acc[mi][nj][1] + bo,
                                   acc[mi][nj][2] + bo, acc[mi][nj][3] + bo);
            *(float4*)(z + ((size_t)b * CIN + o) * LEN + l) = v;
            s[nj]  += (v.x + v.y) + (v.z + v.w);
            s2[nj] += (v.x * v.x + v.y * v.y) + (v.z * v.z + v.w * v.w);
        }
    }
    #pragma unroll
    for (int nj = 0; nj < 4; nj++) {
        float sv = s[nj], qv = s2[nj];
        sv += __shfl_xor(sv, 16); sv += __shfl_xor(sv, 32);
        qv += __shfl_xor(qv, 16); qv += __shfl_xor(qv, 32);
        if (quad == 0) {
            int o = o0 + wn * 64 + nj * 16 + ln;
            atomicAdd(&bns[o], sv);
            atomicAdd(&bnq[o], qv);
        }
    }
}

// ---------------------------------------------------------------------------
// Kernel 4: BN normalize (batch stats, biased var) + residual, in-place.
// ---------------------------------------------------------------------------
__global__ __launch_bounds__(256) void bn_kernel(
    float* __restrict__ z, const float* __restrict__ x,
    const float* __restrict__ bns, const float* __restrict__ bnq,
    const float* __restrict__ gamma, const float* __restrict__ beta)
{
    size_t i4 = (size_t)blockIdx.x * 256 + threadIdx.x;
    size_t base = i4 << 2;
    int c = (int)((base >> 12) & (CIN - 1));
    const float invn = 1.0f / (BATCH * LEN);
    float mean = bns[c] * invn;
    float var  = bnq[c] * invn - mean * mean;
    float sc = gamma[c] * rsqrtf(var + 1e-5f);
    float sh = beta[c] - mean * sc;
    float4 zv = *(const float4*)(z + base);
    float4 xv = *(const float4*)(x + base);
    float4 o;
    o.x = zv.x * sc + sh + xv.x;
    o.y = zv.y * sc + sh + xv.y;
    o.z = zv.z * sc + sh + xv.z;
    o.w = zv.w * sc + sh + xv.w;
    *(float4*)(z + base) = o;
}

// ---------------------------------------------------------------------------
extern "C" void kernel_launch(void* const* d_in, const int* in_sizes, int n_in,
                              void* d_out, int out_size, void* d_ws, size_t ws_size,
                              hipStream_t stream)
{
    const float* x     = (const float*)d_in[0];
    const float* tw    = (const float*)d_in[1];
    const float* tb    = (const float*)d_in[2];
    const float* pw    = (const float*)d_in[3];
    const float* pb    = (const float*)d_in[4];
    const float* gw    = (const float*)d_in[5];
    const float* gb    = (const float*)d_in[6];
    const float* wzw   = (const float*)d_in[7];
    const float* wzb   = (const float*)d_in[8];
    const float* gamma = (const float*)d_in[9];
    const float* beta  = (const float*)d_in[10];

    float* out = (float*)d_out;

    half_t* xhT    = (half_t*)d_ws;                              // 33.6 MB
    half_t* thetaT = xhT    + (size_t)BATCH * LEN * CIN;         // 16.8 MB
    half_t* phiT   = thetaT + (size_t)BATCH * LEN * CI;          //  8.4 MB
    half_t* gH     = phiT   + (size_t)BATCH * KLEN * CI;         //  8.4 MB
    half_t* yhT    = gH     + (size_t)BATCH * CI * KLEN;         // 16.8 MB
    half_t* Wh     = yhT    + (size_t)BATCH * LEN * CI;          // 768 KB
    half_t* wzh    = Wh     + (size_t)768 * 512;                 // 256 KB
    float*  bns    = (float*)(wzh + (size_t)512 * 256);
    float*  bnq    = bns + CIN;

    hipMemsetAsync(bns, 0, 2 * CIN * sizeof(float), stream);

    wconv_kernel<<<256, 256, 0, stream>>>(tw, pw, gw, wzw, Wh, wzh);

    xpose_kernel<<<dim3(LEN / 64, CIN / 64, BATCH), 256, 0, stream>>>(x, xhT);

    projmm_kernel<<<dim3(LEN / 128, 6, BATCH), 256, 0, stream>>>(
        xhT, Wh, tb, pb, gb, thetaT, phiT, gH);

    attn_kernel<<<dim3(BATCH, LEN / 64), 256, 0, stream>>>(
        thetaT, phiT, gH, yhT);

    zmm_kernel<<<dim3(LEN / 128, CIN / 128, BATCH), 256, 0, stream>>>(
        yhT, wzh, wzb, out, bns, bnq);

    bn_kernel<<<(BATCH * CIN * LEN) / 4 / 256, 256, 0, stream>>>(
        out, x, bns, bnq, gamma, beta);
}